// Round 1
// baseline (2102.661 us; speedup 1.0000x reference)
//
#include <hip/hip_runtime.h>

#define BATCH   32768
#define PEDS    16                 // peds per block (2 scenes)
#define NBLK    (BATCH/PEDS)       // 2048 blocks
#define SEQLEN  12

// ws layout (floats): w1n[64*64*3] @0, w2n[32*64*3] @12288, w3n[32*32*3] @18432

__global__ void wn_prep(const float* __restrict__ v1, const float* __restrict__ g1,
                        const float* __restrict__ v2, const float* __restrict__ g2,
                        const float* __restrict__ v3, const float* __restrict__ g3,
                        float* __restrict__ wsw)
{
    int t = threadIdx.x;
    if (t < 64) {
        const float* v = v1 + t*192;
        float s = 0.f;
        for (int j = 0; j < 192; j++) s += v[j]*v[j];
        float sc = g1[t] / sqrtf(s);
        float* w = wsw + t*192;
        for (int j = 0; j < 192; j++) w[j] = v[j]*sc;
    } else if (t < 96) {
        int o = t - 64;
        const float* v = v2 + o*192;
        float s = 0.f;
        for (int j = 0; j < 192; j++) s += v[j]*v[j];
        float sc = g2[o] / sqrtf(s);
        float* w = wsw + 12288 + o*192;
        for (int j = 0; j < 192; j++) w[j] = v[j]*sc;
    } else if (t < 128) {
        int o = t - 96;
        const float* v = v3 + o*96;
        float s = 0.f;
        for (int j = 0; j < 96; j++) s += v[j]*v[j];
        float sc = g3[o] / sqrtf(s);
        float* w = wsw + 18432 + o*96;
        for (int j = 0; j < 96; j++) w[j] = v[j]*sc;
    }
}

__global__ __launch_bounds__(256, 2)
void enc_main(const float* __restrict__ obs,
              const float* __restrict__ Wse, const float* __restrict__ bse,
              const float* __restrict__ b1,  const float* __restrict__ b2,
              const float* __restrict__ b3,
              const float* __restrict__ Whp, const float* __restrict__ bhp,
              const float* __restrict__ wsw,
              float* __restrict__ out)
{
    // state + intermediates, ped-fastest so consecutive lanes hit distinct banks
    __shared__ float x [64][8][PEDS];    // obs_emb, 32 KB
    __shared__ float s1[64][6][PEDS];    // 24 KB
    __shared__ float s2[32][4][PEDS];    //  8 KB
    __shared__ float sf[64][PEDS];       //  4 KB (post-reshape feature)
    __shared__ float mxs[64][PEDS/8];    // scene max
    __shared__ float relb[PEDS][2];

    const int tid  = threadIdx.x;
    const int ped  = tid & (PEDS-1);
    const int sub  = tid >> 4;           // 0..15
    const int gped = blockIdx.x * PEDS + ped;

    // ---- initial spatial embedding: x[c][tau][ped] ----
    for (int j = 0; j < 4; j++) {
        int c = sub*4 + j;
        float w0 = Wse[c*2+0], w1 = Wse[c*2+1], bb = bse[c];
        for (int tau = 0; tau < 8; tau++) {
            float o0 = obs[(tau*BATCH + gped)*2 + 0];
            float o1 = obs[(tau*BATCH + gped)*2 + 1];
            x[c][tau][ped] = fmaf(w0, o0, fmaf(w1, o1, bb));
        }
    }
    __syncthreads();

    for (int st = 0; st < SEQLEN; st++) {
        // ---- conv1: 64ch x 8t -> 64ch x 6t ; this thread: o = sub*4 + 0..3 ----
        {
            float acc[4][6];
            #pragma unroll
            for (int o = 0; o < 4; o++) {
                float bb = b1[sub*4 + o];
                #pragma unroll
                for (int t = 0; t < 6; t++) acc[o][t] = bb;
            }
            for (int c0 = 0; c0 < 64; c0 += 8) {
                float xv[8][8];
                #pragma unroll
                for (int i = 0; i < 8; i++)
                    #pragma unroll
                    for (int sl = 0; sl < 8; sl++)
                        xv[i][sl] = x[c0+i][sl][ped];
                #pragma unroll
                for (int o = 0; o < 4; o++) {
                    const float* w = wsw + ((sub*4 + o)*64 + c0)*3;
                    #pragma unroll
                    for (int i = 0; i < 8; i++) {
                        float w0 = w[i*3+0], w1 = w[i*3+1], w2 = w[i*3+2];
                        #pragma unroll
                        for (int t = 0; t < 6; t++)
                            acc[o][t] = fmaf(w0, xv[i][t],
                                        fmaf(w1, xv[i][t+1],
                                        fmaf(w2, xv[i][t+2], acc[o][t])));
                    }
                }
            }
            #pragma unroll
            for (int o = 0; o < 4; o++)
                #pragma unroll
                for (int t = 0; t < 6; t++)
                    s1[sub*4 + o][t][ped] = fmaxf(acc[o][t], 0.f);
        }
        __syncthreads();

        // ---- conv2: 64ch x 6t -> 32ch x 4t ; this thread: o = sub*2 + 0..1 ----
        {
            float acc[2][4];
            #pragma unroll
            for (int o = 0; o < 2; o++) {
                float bb = b2[sub*2 + o];
                #pragma unroll
                for (int t = 0; t < 4; t++) acc[o][t] = bb;
            }
            for (int c0 = 0; c0 < 64; c0 += 8) {
                float sv[8][6];
                #pragma unroll
                for (int i = 0; i < 8; i++)
                    #pragma unroll
                    for (int sl = 0; sl < 6; sl++)
                        sv[i][sl] = s1[c0+i][sl][ped];
                #pragma unroll
                for (int o = 0; o < 2; o++) {
                    const float* w = wsw + 12288 + ((sub*2 + o)*64 + c0)*3;
                    #pragma unroll
                    for (int i = 0; i < 8; i++) {
                        float w0 = w[i*3+0], w1 = w[i*3+1], w2 = w[i*3+2];
                        #pragma unroll
                        for (int t = 0; t < 4; t++)
                            acc[o][t] = fmaf(w0, sv[i][t],
                                        fmaf(w1, sv[i][t+1],
                                        fmaf(w2, sv[i][t+2], acc[o][t])));
                    }
                }
            }
            #pragma unroll
            for (int o = 0; o < 2; o++)
                #pragma unroll
                for (int t = 0; t < 4; t++)
                    s2[sub*2 + o][t][ped] = fmaxf(acc[o][t], 0.f);
        }
        __syncthreads();

        // ---- conv3: 32ch x 4t -> 32ch x 2t, then reshape to sf[64] ----
        {
            float acc[2][2];
            #pragma unroll
            for (int o = 0; o < 2; o++) {
                float bb = b3[sub*2 + o];
                acc[o][0] = bb; acc[o][1] = bb;
            }
            for (int c0 = 0; c0 < 32; c0 += 8) {
                float sv[8][4];
                #pragma unroll
                for (int i = 0; i < 8; i++)
                    #pragma unroll
                    for (int sl = 0; sl < 4; sl++)
                        sv[i][sl] = s2[c0+i][sl][ped];
                #pragma unroll
                for (int o = 0; o < 2; o++) {
                    const float* w = wsw + 18432 + ((sub*2 + o)*32 + c0)*3;
                    #pragma unroll
                    for (int i = 0; i < 8; i++) {
                        float w0 = w[i*3+0], w1 = w[i*3+1], w2 = w[i*3+2];
                        #pragma unroll
                        for (int t = 0; t < 2; t++)
                            acc[o][t] = fmaf(w0, sv[i][t],
                                        fmaf(w1, sv[i][t+1],
                                        fmaf(w2, sv[i][t+2], acc[o][t])));
                    }
                }
            }
            #pragma unroll
            for (int o = 0; o < 2; o++) {
                int oc = sub*2 + o;
                #pragma unroll
                for (int tt = 0; tt < 2; tt++)
                    sf[oc*2 + tt][ped] = fmaxf(acc[o][tt], 0.f);  // s[b, o*2+tt]
            }
        }
        __syncthreads();

        // ---- per-scene segment max (scenes of 8 peds) ----
        if (tid < 64*(PEDS/8)) {
            int c = tid & 63, scn = tid >> 6;
            float m = sf[c][scn*8];
            #pragma unroll
            for (int j = 1; j < 8; j++) m = fmaxf(m, sf[c][scn*8 + j]);
            mxs[c][scn] = m;
        }
        __syncthreads();

        // ---- hidden2pos: rel = [s, mx] @ Whp^T + bhp ----
        if (sub < 2) {
            int d = sub;
            int scn = ped >> 3;
            float r = bhp[d];
            for (int c = 0; c < 64; c++) r = fmaf(Whp[d*128 + c],      sf[c][ped],  r);
            for (int c = 0; c < 64; c++) r = fmaf(Whp[d*128 + 64 + c], mxs[c][scn], r);
            relb[ped][d] = r;
            out[(st*BATCH + gped)*2 + d] = r;
        }
        __syncthreads();

        // ---- shift window + append dec = rel @ Wse^T + bse ----
        {
            float r0 = relb[ped][0], r1 = relb[ped][1];
            for (int j = 0; j < 4; j++) {
                int c = sub*4 + j;
                float t1 = x[c][1][ped], t2 = x[c][2][ped], t3 = x[c][3][ped],
                      t4 = x[c][4][ped], t5 = x[c][5][ped], t6 = x[c][6][ped],
                      t7 = x[c][7][ped];
                x[c][0][ped] = t1; x[c][1][ped] = t2; x[c][2][ped] = t3;
                x[c][3][ped] = t4; x[c][4][ped] = t5; x[c][5][ped] = t6;
                x[c][6][ped] = t7;
                x[c][7][ped] = fmaf(Wse[c*2+0], r0, fmaf(Wse[c*2+1], r1, bse[c]));
            }
        }
        __syncthreads();
    }
}

extern "C" void kernel_launch(void* const* d_in, const int* in_sizes, int n_in,
                              void* d_out, int out_size, void* d_ws, size_t ws_size,
                              hipStream_t stream)
{
    const float* obs  = (const float*)d_in[0];
    // d_in[1] last_pos, d_in[2] last_pos_rel: dead state (never reaches output)
    const float* Wse  = (const float*)d_in[3];
    const float* bse  = (const float*)d_in[4];
    const float* v1   = (const float*)d_in[5];
    const float* g1   = (const float*)d_in[6];
    const float* b1   = (const float*)d_in[7];
    const float* v2   = (const float*)d_in[8];
    const float* g2   = (const float*)d_in[9];
    const float* b2   = (const float*)d_in[10];
    const float* v3   = (const float*)d_in[11];
    const float* g3   = (const float*)d_in[12];
    const float* b3   = (const float*)d_in[13];
    const float* Whp  = (const float*)d_in[14];
    const float* bhp  = (const float*)d_in[15];
    // d_in[16] seq_start_end: structurally seg = ped>>3 ; d_in[17] seq_len = 12

    float* wsw = (float*)d_ws;       // 21504 floats of normalized weights
    float* out = (float*)d_out;

    wn_prep<<<1, 128, 0, stream>>>(v1, g1, v2, g2, v3, g3, wsw);
    enc_main<<<NBLK, 256, 0, stream>>>(obs, Wse, bse, b1, b2, b3, Whp, bhp, wsw, out);
}